// Round 5
// baseline (633.653 us; speedup 1.0000x reference)
//
#include <hip/hip_runtime.h>

#define NN 262144
#define KK 1024
#define DD 64
#define DECAY 0.99f
#define ONE_MINUS_DECAY 0.01f
#define EPSF 1e-5f
#define COMMIT 0.25f

// padded bf16 codebook planes: 144B per code row (72 bf16, 64 used + 8 pad)
#define ROWB 144
#define CHUNK_CODES 128
#define CHUNK_BYTES (CHUNK_CODES * ROWB * 2)   // hi plane + lo plane = 36864
#define PLANE_BYTES (CHUNK_CODES * ROWB)       // 18432

typedef __bf16 bf16x8 __attribute__((ext_vector_type(8)));
typedef unsigned short ushort8 __attribute__((ext_vector_type(8)));
typedef float float4v __attribute__((ext_vector_type(4)));

__device__ inline unsigned short bf16rne(float f) {
    unsigned int u = __float_as_uint(f);
    u += 0x7fffu + ((u >> 16) & 1u);
    return (unsigned short)(u >> 16);
}

// --- fused: split codebook into chunked padded bf16 hi/lo planes + 0.5||c||^2
__global__ __launch_bounds__(256) void k_prep(const float* __restrict__ cb,
                                              unsigned char* __restrict__ cbhl,
                                              float* __restrict__ csq_half) {
    int e = blockIdx.x * 256 + threadIdx.x;      // 0..65535
    int k = e >> 6, d = e & 63;
    int c = k >> 7, kl = k & 127;
    float f = cb[e];
    unsigned short h = bf16rne(f);
    float hf = __uint_as_float((unsigned int)h << 16);
    unsigned short l = bf16rne(f - hf);
    unsigned char* base = cbhl + (size_t)c * CHUNK_BYTES;
    *(unsigned short*)(base + kl * ROWB + d * 2) = h;
    *(unsigned short*)(base + PLANE_BYTES + kl * ROWB + d * 2) = l;
    // wave == one code row (d == lane): reduce c^2
    float s = f * f;
#pragma unroll
    for (int off = 32; off > 0; off >>= 1) s += __shfl_down(s, off);
    if (d == 0) csq_half[k] = 0.5f * s;
}

// --- assignment: split-bf16 MFMA, packed-uint top-2, exact fp32 refinement --
// wave = 64 rows (4 m-tiles x 16), block = 4 waves = 256 rows, grid = NN/256.
// dp = (0.5||c||^2 - x.c) + (||x||^2/2... actually xsq1 = 0.5||x||^2? no:
// we add xsq1 = 0.5*||x||^2*... see below) -- biased positive so raw float
// bits are monotone; low 10 bits carry the code index; top-2 = min/max/min.
__global__ __launch_bounds__(256, 3) void k_assign(
    const float* __restrict__ x, const float* __restrict__ cb,
    const unsigned char* __restrict__ cbhl, const float* __restrict__ csq_half,
    float* __restrict__ quant, int* __restrict__ idx_int,
    int* __restrict__ counts, float* __restrict__ loss_acc)
{
    __shared__ __align__(16) unsigned char ldsbuf[CHUNK_BYTES];

    const int tid  = threadIdx.x;
    const int lane = tid & 63;
    const int wave = tid >> 6;
    const int col  = lane & 15;
    const int quad = lane >> 4;
    const int rowbase = blockIdx.x * 256 + wave * 64;

    // ---- negated split-bf16 A fragments, 4 m-tiles x 2 k-halves; and 0.5||x||^2
    bf16x8 nah[4][2], nal[4][2];
    float xsq1[16];   // [mt*4+r] = 0.5*||x_row||^2 + 1, row = mt*16+quad*4+r
    {
        float xsqm[4];
#pragma unroll
        for (int mt = 0; mt < 4; ++mt) {
            const float* xb = x + (size_t)(rowbase + mt * 16 + col) * DD + quad * 8;
            float s = 0.f;
#pragma unroll
            for (int kh = 0; kh < 2; ++kh) {
                float4 f0 = *(const float4*)(xb + kh * 32);
                float4 f1 = *(const float4*)(xb + kh * 32 + 4);
                s += f0.x * f0.x + f0.y * f0.y + f0.z * f0.z + f0.w * f0.w;
                s += f1.x * f1.x + f1.y * f1.y + f1.z * f1.z + f1.w * f1.w;
                float fv[8] = {f0.x, f0.y, f0.z, f0.w, f1.x, f1.y, f1.z, f1.w};
                ushort8 uh, ul;
#pragma unroll
                for (int j = 0; j < 8; ++j) {
                    float nf = -fv[j];
                    unsigned short h = bf16rne(nf);
                    float hf = __uint_as_float((unsigned int)h << 16);
                    uh[j] = h;
                    ul[j] = bf16rne(nf - hf);
                }
                nah[mt][kh] = __builtin_bit_cast(bf16x8, uh);
                nal[mt][kh] = __builtin_bit_cast(bf16x8, ul);
            }
            s += __shfl_xor(s, 16);
            s += __shfl_xor(s, 32);          // full row norm^2 at all quads
            xsqm[mt] = s;
        }
#pragma unroll
        for (int mt = 0; mt < 4; ++mt)
#pragma unroll
            for (int r = 0; r < 4; ++r)
                xsq1[mt * 4 + r] = 0.5f * __shfl(xsqm[mt], quad * 4 + r) + 1.0f;
    }

    // ---- packed top-2 (value-bits | code) per 16 rows/lane
    unsigned int best[16], sec[16];
#pragma unroll
    for (int j = 0; j < 16; ++j) { best[j] = 0xFFFFFFFFu; sec[j] = 0xFFFFFFFFu; }

    for (int chunk = 0; chunk < KK / CHUNK_CODES; ++chunk) {
        __syncthreads();
        const uint4* src = (const uint4*)(cbhl + (size_t)chunk * CHUNK_BYTES);
        uint4* dst = (uint4*)ldsbuf;
#pragma unroll
        for (int i = 0; i < CHUNK_BYTES / 16 / 256; ++i)   // 9 iters
            dst[tid + i * 256] = src[tid + i * 256];
        __syncthreads();

#pragma unroll
        for (int ct = 0; ct < CHUNK_CODES / 16; ++ct) {    // 8 code-tiles
            const int code_local = ct * 16 + col;
            const unsigned int codeCol = chunk * CHUNK_CODES + code_local;
            const unsigned char* bp = ldsbuf + code_local * ROWB + quad * 16;
            bf16x8 bh0 = __builtin_bit_cast(bf16x8, *(const uint4*)(bp));
            bf16x8 bh1 = __builtin_bit_cast(bf16x8, *(const uint4*)(bp + 64));
            bf16x8 bl0 = __builtin_bit_cast(bf16x8, *(const uint4*)(bp + PLANE_BYTES));
            bf16x8 bl1 = __builtin_bit_cast(bf16x8, *(const uint4*)(bp + PLANE_BYTES + 64));
            float csq = csq_half[codeCol];

#pragma unroll
            for (int mt = 0; mt < 4; ++mt) {
                float4v a = {csq, csq, csq, csq};
                a = __builtin_amdgcn_mfma_f32_16x16x32_bf16(nah[mt][0], bh0, a, 0, 0, 0);
                a = __builtin_amdgcn_mfma_f32_16x16x32_bf16(nah[mt][1], bh1, a, 0, 0, 0);
                a = __builtin_amdgcn_mfma_f32_16x16x32_bf16(nah[mt][0], bl0, a, 0, 0, 0);
                a = __builtin_amdgcn_mfma_f32_16x16x32_bf16(nah[mt][1], bl1, a, 0, 0, 0);
                a = __builtin_amdgcn_mfma_f32_16x16x32_bf16(nal[mt][0], bh0, a, 0, 0, 0);
                a = __builtin_amdgcn_mfma_f32_16x16x32_bf16(nal[mt][1], bh1, a, 0, 0, 0);
#pragma unroll
                for (int r = 0; r < 4; ++r) {
                    float dpf = a[r] + xsq1[mt * 4 + r];   // >= ~1: bits monotone
                    unsigned int u = (__float_as_uint(dpf) & 0xFFFFFC00u) | codeCol;
                    unsigned int hi = best[mt * 4 + r] > u ? best[mt * 4 + r] : u;
                    best[mt * 4 + r] = best[mt * 4 + r] < u ? best[mt * 4 + r] : u;
                    sec[mt * 4 + r] = sec[mt * 4 + r] < hi ? sec[mt * 4 + r] : hi;
                }
            }
        }
    }

    // ---- merge top-2 across the 16 col-lanes (packed: pure min/max)
#pragma unroll
    for (int m = 1; m <= 8; m <<= 1) {
#pragma unroll
        for (int j = 0; j < 16; ++j) {
            unsigned int ob = __shfl_xor(best[j], m, 16);
            unsigned int os = __shfl_xor(sec[j],  m, 16);
            unsigned int hi = best[j] > ob ? best[j] : ob;
            best[j] = best[j] < ob ? best[j] : ob;
            unsigned int s2 = sec[j] < os ? sec[j] : os;
            sec[j] = s2 < hi ? s2 : hi;
        }
    }

    // ---- stash (k1,k2) per row in LDS (reuse staging buffer)
    __syncthreads();
    int2* scratch = (int2*)ldsbuf;
    if (col == 0) {
#pragma unroll
        for (int j = 0; j < 16; ++j) {
            int row_local = (j >> 2) * 16 + quad * 4 + (j & 3);
            scratch[wave * 64 + row_local] =
                make_int2((int)(best[j] & 1023u), (int)(sec[j] & 1023u));
        }
    }
    __syncthreads();

    // ---- exact fp32 refinement: 1 lane per row
    const int grow = rowbase + lane;
    int2 kk = scratch[wave * 64 + lane];
    const float4* xp  = (const float4*)(x  + (size_t)grow * DD);
    const float4* c1p = (const float4*)(cb + (size_t)kk.x * DD);
    const float4* c2p = (const float4*)(cb + (size_t)kk.y * DD);
    float p1 = 0.f, p2 = 0.f;
#pragma unroll
    for (int j = 0; j < 16; ++j) {
        float4 xv = xp[j];
        float4 c1 = c1p[j], c2 = c2p[j];
        p1 += xv.x * c1.x + xv.y * c1.y + xv.z * c1.z + xv.w * c1.w;
        p2 += xv.x * c2.x + xv.y * c2.y + xv.z * c2.z + xv.w * c2.w;
    }
    float d1 = csq_half[kk.x] - p1;
    float d2 = csq_half[kk.y] - p2;
    bool pick1 = (d1 < d2) || (d1 == d2 && kk.x < kk.y);
    int w = pick1 ? kk.x : kk.y;

    const float4* qp = (const float4*)(cb + (size_t)w * DD);
    float4* op = (float4*)(quant + (size_t)grow * DD);
    float err = 0.f;
#pragma unroll
    for (int j = 0; j < 16; ++j) {
        float4 xv = xp[j];
        float4 q = qp[j];
        op[j] = q;
        float ex = q.x - xv.x, ey = q.y - xv.y;
        float ez = q.z - xv.z, ew = q.w - xv.w;
        err += ex * ex + ey * ey + ez * ez + ew * ew;
    }
#pragma unroll
    for (int off = 32; off > 0; off >>= 1) err += __shfl_down(err, off);
    if (lane == 0) atomicAdd(loss_acc, err);
    idx_int[grow] = w;
    atomicAdd(&counts[w], 1);
}

// --- single block: EMA cluster size, n-reduce, smoothed, scan, loss ---------
__global__ __launch_bounds__(1024) void k_mid(
    const int* __restrict__ counts, const float* __restrict__ ema_cs,
    const float* __restrict__ loss_acc,
    float* __restrict__ new_cs, float* __restrict__ loss_out,
    float* __restrict__ smoothed_inv, int* __restrict__ offsets,
    int* __restrict__ cursor)
{
    int t = threadIdx.x; int lane = t & 63; int w = t >> 6;
    int cnt = counts[t];
    float ncs = DECAY * ema_cs[t] + ONE_MINUS_DECAY * (float)cnt;

    __shared__ float wsumf[16];
    __shared__ int wsumi[16];
    __shared__ float ntot_s;

    float s = ncs;
#pragma unroll
    for (int off = 32; off > 0; off >>= 1) s += __shfl_down(s, off);
    if (lane == 0) wsumf[w] = s;

    int v = cnt;
#pragma unroll
    for (int off = 1; off < 64; off <<= 1) {
        int u = __shfl_up(v, off);
        if (lane >= off) v += u;
    }
    if (lane == 63) wsumi[w] = v;
    __syncthreads();
    if (t == 0) {
        float tt = 0.f;
        for (int i = 0; i < 16; ++i) tt += wsumf[i];
        ntot_s = tt;
    }
    if (w == 0 && lane < 16) {
        int u = wsumi[lane]; int vv = u;
#pragma unroll
        for (int off = 1; off < 16; off <<= 1) {
            int p = __shfl_up(vv, off, 16);
            if ((lane & 15) >= off) vv += p;
        }
        wsumi[lane] = vv - u;
    }
    __syncthreads();
    float n = ntot_s;

    float sm = (ncs + EPSF) / (n + (float)KK * EPSF) * n;
    new_cs[t] = ncs;
    smoothed_inv[t] = 1.0f / sm;

    int excl = wsumi[w] + v - cnt;
    offsets[t] = excl;
    cursor[t] = excl;

    if (t == 0) loss_out[0] = COMMIT * loss_acc[0] / (float)(NN * DD);
}

// --- scatter rows into per-code segments: one int2 {row, code} per position -
__global__ __launch_bounds__(256) void k_scatter(
    int* __restrict__ idx_inout, int* __restrict__ cursor,
    int2* __restrict__ pairs)
{
    int i = blockIdx.x * 256 + threadIdx.x;
    int k = idx_inout[i];
    int pos = atomicAdd(&cursor[k], 1);
    pairs[pos] = make_int2(i, k);
    ((float*)idx_inout)[i] = (float)k;   // own-element read happened above
}

// --- balanced segment sum: each wave 64 sorted rows, shfl-broadcast keys ----
__global__ __launch_bounds__(256) void k_segsum(
    const float* __restrict__ x, const int2* __restrict__ pairs,
    float* __restrict__ dw)
{
    int w = blockIdx.x * 4 + (threadIdx.x >> 6);   // 4096 waves total
    int lane = threadIdx.x & 63;
    int base = w * 64;
    int2 mine = pairs[base + lane];                // coalesced 512B per wave
    float acc = 0.f;
    int cur = __shfl(mine.y, 0);
    for (int r = 0; r < 64; ++r) {
        int code = __shfl(mine.y, r);
        int row  = __shfl(mine.x, r);
        if (code != cur) {                         // wave-uniform
            atomicAdd(&dw[cur * DD + lane], acc);
            acc = 0.f; cur = code;
        }
        acc += x[(size_t)row * DD + lane];         // 256B coalesced gather
    }
    atomicAdd(&dw[cur * DD + lane], acc);
}

// --- EMA weight update + codebook normalize --------------------------------
__global__ __launch_bounds__(256) void k_final(
    const float* __restrict__ dw, const float* __restrict__ ema_w,
    const float* __restrict__ smoothed_inv,
    float* __restrict__ new_ema_w, float* __restrict__ new_cb)
{
    int i = blockIdx.x * 256 + threadIdx.x;
    int k = i >> 6;
    float nw = DECAY * ema_w[i] + ONE_MINUS_DECAY * dw[i];
    new_ema_w[i] = nw;
    new_cb[i] = nw * smoothed_inv[k];
}

extern "C" void kernel_launch(void* const* d_in, const int* in_sizes, int n_in,
                              void* d_out, int out_size, void* d_ws, size_t ws_size,
                              hipStream_t stream)
{
    const float* x      = (const float*)d_in[0];
    const float* cb     = (const float*)d_in[1];
    const float* ema_cs = (const float*)d_in[2];
    const float* ema_w  = (const float*)d_in[3];

    float* out      = (float*)d_out;
    float* quant    = out;                                   // [N*D]
    float* loss_out = out + (size_t)NN * DD;                 // [1]
    int*   idx_reg  = (int*)(out + (size_t)NN * DD + 1);     // [N] (float slot)
    float* new_cb   = out + (size_t)NN * DD + 1 + NN;        // [K*D]
    float* new_cs   = new_cb + (size_t)KK * DD;              // [K]
    float* new_emaw = new_cs + KK;                           // [K*D]

    char* ws = (char*)d_ws;
    float* loss_acc     = (float*)(ws + 0);                  // 256 B
    int*   counts       = (int*)(ws + 256);                  // 4 KB
    float* dw           = (float*)(ws + 4352);               // 256 KB
    int*   offsets      = (int*)(ws + 266496);               // 4 KB
    int*   cursor       = (int*)(ws + 270592);               // 4 KB
    float* csq_half     = (float*)(ws + 274688);             // 4 KB
    float* smoothed_inv = (float*)(ws + 278784);             // 4 KB
    unsigned char* cbhl = (unsigned char*)(ws + 282880);     // 288 KB
    int2*  pairs        = (int2*)(ws + 577792);              // 2 MB

    hipMemsetAsync(d_ws, 0, 266496, stream);   // loss_acc + counts + dw

    k_prep   <<<KK * DD / 256, 256, 0, stream>>>(cb, cbhl, csq_half);
    k_assign <<<NN / 256, 256, 0, stream>>>(x, cb, cbhl, csq_half, quant,
                                            idx_reg, counts, loss_acc);
    k_mid    <<<1, 1024, 0, stream>>>(counts, ema_cs, loss_acc, new_cs,
                                      loss_out, smoothed_inv, offsets, cursor);
    k_scatter<<<NN / 256, 256, 0, stream>>>(idx_reg, cursor, pairs);
    k_segsum <<<NN / 256, 256, 0, stream>>>(x, pairs, dw);
    k_final  <<<KK * DD / 256, 256, 0, stream>>>(dw, ema_w, smoothed_inv,
                                                 new_emaw, new_cb);
}

// Round 6
// 397.078 us; speedup vs baseline: 1.5958x; 1.5958x over previous
//
#include <hip/hip_runtime.h>

#define NN 262144
#define KK 1024
#define DD 64
#define DECAY 0.99f
#define ONE_MINUS_DECAY 0.01f
#define EPSF 1e-5f
#define COMMIT 0.25f

// padded bf16 codebook planes: 144B per code row (72 bf16, 64 used + 8 pad)
#define ROWB 144
#define CHUNK_CODES 128
#define CHUNK_BYTES (CHUNK_CODES * ROWB * 2)   // hi plane + lo plane = 36864
#define PLANE_BYTES (CHUNK_CODES * ROWB)       // 18432

typedef __bf16 bf16x8 __attribute__((ext_vector_type(8)));
typedef unsigned short ushort8 __attribute__((ext_vector_type(8)));
typedef float float4v __attribute__((ext_vector_type(4)));

__device__ inline unsigned short bf16rne(float f) {
    unsigned int u = __float_as_uint(f);
    u += 0x7fffu + ((u >> 16) & 1u);
    return (unsigned short)(u >> 16);
}

// --- fused: split codebook into chunked padded bf16 hi/lo planes + 0.5||c||^2
__global__ __launch_bounds__(256) void k_prep(const float* __restrict__ cb,
                                              unsigned char* __restrict__ cbhl,
                                              float* __restrict__ csq_half) {
    int e = blockIdx.x * 256 + threadIdx.x;      // 0..65535
    int k = e >> 6, d = e & 63;
    int c = k >> 7, kl = k & 127;
    float f = cb[e];
    unsigned short h = bf16rne(f);
    float hf = __uint_as_float((unsigned int)h << 16);
    unsigned short l = bf16rne(f - hf);
    unsigned char* base = cbhl + (size_t)c * CHUNK_BYTES;
    *(unsigned short*)(base + kl * ROWB + d * 2) = h;
    *(unsigned short*)(base + PLANE_BYTES + kl * ROWB + d * 2) = l;
    float s = f * f;
#pragma unroll
    for (int off = 32; off > 0; off >>= 1) s += __shfl_down(s, off);
    if (d == 0) csq_half[k] = 0.5f * s;
}

// --- assignment: split-bf16 MFMA, packed-uint top-2, exact fp32 refinement --
// wave = 32 rows (2 m-tiles x 16) -> state ~90 VGPRs, fits the 128 cap from
// __launch_bounds__(256,4). R5's 64-row variant needed ~130 and spilled
// (WRITE_SIZE 74->900 MB). Bias (0.5||x||^2 + 1) folded into the MFMA acc
// init so acc = 0.5||x-c||^2 + 1 >= 1 directly: raw float bits monotone,
// low 10 bits carry the code, top-2 = and_or + min/max/min (4 VALU per dp).
__global__ __launch_bounds__(256, 4) void k_assign(
    const float* __restrict__ x, const float* __restrict__ cb,
    const unsigned char* __restrict__ cbhl, const float* __restrict__ csq_half,
    float* __restrict__ quant, int* __restrict__ idx_int,
    int* __restrict__ counts, float* __restrict__ loss_acc)
{
    __shared__ __align__(16) unsigned char ldsbuf[CHUNK_BYTES];

    const int tid  = threadIdx.x;
    const int lane = tid & 63;
    const int wave = tid >> 6;
    const int col  = lane & 15;
    const int quad = lane >> 4;
    const int rowbase = blockIdx.x * 128 + wave * 32;

    // ---- negated split-bf16 A fragments (2 m-tiles x 2 k-halves) + bias
    bf16x8 nah[2][2], nal[2][2];
    float xsq1[8];      // [mt*4+r] = 0.5*||x_row||^2 + 1, row = mt*16+quad*4+r
    {
        float xsqm[2];
#pragma unroll
        for (int mt = 0; mt < 2; ++mt) {
            const float* xb = x + (size_t)(rowbase + mt * 16 + col) * DD + quad * 8;
            float s = 0.f;
#pragma unroll
            for (int kh = 0; kh < 2; ++kh) {
                float4 f0 = *(const float4*)(xb + kh * 32);
                float4 f1 = *(const float4*)(xb + kh * 32 + 4);
                s += f0.x * f0.x + f0.y * f0.y + f0.z * f0.z + f0.w * f0.w;
                s += f1.x * f1.x + f1.y * f1.y + f1.z * f1.z + f1.w * f1.w;
                float fv[8] = {f0.x, f0.y, f0.z, f0.w, f1.x, f1.y, f1.z, f1.w};
                ushort8 uh, ul;
#pragma unroll
                for (int j = 0; j < 8; ++j) {
                    float nf = -fv[j];
                    unsigned short h = bf16rne(nf);
                    float hf = __uint_as_float((unsigned int)h << 16);
                    uh[j] = h;
                    ul[j] = bf16rne(nf - hf);
                }
                nah[mt][kh] = __builtin_bit_cast(bf16x8, uh);
                nal[mt][kh] = __builtin_bit_cast(bf16x8, ul);
            }
            s += __shfl_xor(s, 16);
            s += __shfl_xor(s, 32);          // full row norm^2 at all quads
            xsqm[mt] = s;
        }
#pragma unroll
        for (int mt = 0; mt < 2; ++mt)
#pragma unroll
            for (int r = 0; r < 4; ++r)
                xsq1[mt * 4 + r] = 0.5f * __shfl(xsqm[mt], quad * 4 + r) + 1.0f;
    }

    // ---- packed top-2 (value-bits | code) per 8 rows/lane
    unsigned int best[8], sec[8];
#pragma unroll
    for (int j = 0; j < 8; ++j) { best[j] = 0xFFFFFFFFu; sec[j] = 0xFFFFFFFFu; }

    for (int chunk = 0; chunk < KK / CHUNK_CODES; ++chunk) {
        __syncthreads();
        const uint4* src = (const uint4*)(cbhl + (size_t)chunk * CHUNK_BYTES);
        uint4* dst = (uint4*)ldsbuf;
#pragma unroll
        for (int i = 0; i < CHUNK_BYTES / 16 / 256; ++i)   // 9 iters
            dst[tid + i * 256] = src[tid + i * 256];
        __syncthreads();

        float csqv[8];                       // per-chunk csq preload (L1-hit)
#pragma unroll
        for (int ct = 0; ct < 8; ++ct)
            csqv[ct] = csq_half[chunk * CHUNK_CODES + ct * 16 + col];

#pragma unroll
        for (int ct = 0; ct < CHUNK_CODES / 16; ++ct) {    // 8 code-tiles
            const int code_local = ct * 16 + col;
            const unsigned int codeCol = chunk * CHUNK_CODES + code_local;
            const unsigned char* bp = ldsbuf + code_local * ROWB + quad * 16;
            bf16x8 bh0 = __builtin_bit_cast(bf16x8, *(const uint4*)(bp));
            bf16x8 bh1 = __builtin_bit_cast(bf16x8, *(const uint4*)(bp + 64));
            bf16x8 bl0 = __builtin_bit_cast(bf16x8, *(const uint4*)(bp + PLANE_BYTES));
            bf16x8 bl1 = __builtin_bit_cast(bf16x8, *(const uint4*)(bp + PLANE_BYTES + 64));
            float csq = csqv[ct];

#pragma unroll
            for (int mt = 0; mt < 2; ++mt) {
                float4v a = {csq + xsq1[mt * 4 + 0], csq + xsq1[mt * 4 + 1],
                             csq + xsq1[mt * 4 + 2], csq + xsq1[mt * 4 + 3]};
                a = __builtin_amdgcn_mfma_f32_16x16x32_bf16(nah[mt][0], bh0, a, 0, 0, 0);
                a = __builtin_amdgcn_mfma_f32_16x16x32_bf16(nah[mt][1], bh1, a, 0, 0, 0);
                a = __builtin_amdgcn_mfma_f32_16x16x32_bf16(nah[mt][0], bl0, a, 0, 0, 0);
                a = __builtin_amdgcn_mfma_f32_16x16x32_bf16(nah[mt][1], bl1, a, 0, 0, 0);
                a = __builtin_amdgcn_mfma_f32_16x16x32_bf16(nal[mt][0], bh0, a, 0, 0, 0);
                a = __builtin_amdgcn_mfma_f32_16x16x32_bf16(nal[mt][1], bh1, a, 0, 0, 0);
#pragma unroll
                for (int r = 0; r < 4; ++r) {
                    // a[r] >= 1 -> bits monotone; 4 VALU per dp total
                    unsigned int u = (__float_as_uint(a[r]) & 0xFFFFFC00u) | codeCol;
                    unsigned int j = mt * 4 + r;
                    unsigned int hi = best[j] > u ? best[j] : u;
                    best[j] = best[j] < u ? best[j] : u;
                    sec[j] = sec[j] < hi ? sec[j] : hi;
                }
            }
        }
    }

    // ---- merge top-2 across the 16 col-lanes (packed: pure min/max)
#pragma unroll
    for (int m = 1; m <= 8; m <<= 1) {
#pragma unroll
        for (int j = 0; j < 8; ++j) {
            unsigned int ob = __shfl_xor(best[j], m, 16);
            unsigned int os = __shfl_xor(sec[j],  m, 16);
            unsigned int hi = best[j] > ob ? best[j] : ob;
            best[j] = best[j] < ob ? best[j] : ob;
            unsigned int s2 = sec[j] < os ? sec[j] : os;
            sec[j] = s2 < hi ? s2 : hi;
        }
    }

    // ---- stash (k1,k2) per row in LDS (reuse staging buffer)
    __syncthreads();
    int2* scratch = (int2*)ldsbuf;
    if (col == 0) {
#pragma unroll
        for (int j = 0; j < 8; ++j) {
            int row_local = (j >> 2) * 16 + quad * 4 + (j & 3);
            scratch[wave * 32 + row_local] =
                make_int2((int)(best[j] & 1023u), (int)(sec[j] & 1023u));
        }
    }
    __syncthreads();

    // ---- exact fp32 refinement: 2 lanes per row (dim halves)
    const int r = lane >> 1;              // 0..31 local row
    const int h = lane & 1;               // dim half
    const int grow = rowbase + r;
    int2 kk = scratch[wave * 32 + r];
    const float4* xh = (const float4*)(x + (size_t)grow * DD + h * 32);
    float4 xr4[8];
#pragma unroll
    for (int j = 0; j < 8; ++j) xr4[j] = xh[j];

    float p1 = 0.f, p2 = 0.f;
    const float4* c1p = (const float4*)(cb + (size_t)kk.x * DD + h * 32);
    const float4* c2p = (const float4*)(cb + (size_t)kk.y * DD + h * 32);
#pragma unroll
    for (int j = 0; j < 8; ++j) {
        float4 c1 = c1p[j], c2 = c2p[j];
        p1 += xr4[j].x * c1.x + xr4[j].y * c1.y + xr4[j].z * c1.z + xr4[j].w * c1.w;
        p2 += xr4[j].x * c2.x + xr4[j].y * c2.y + xr4[j].z * c2.z + xr4[j].w * c2.w;
    }
    float d1 = csq_half[kk.x] - (p1 + __shfl_xor(p1, 1));
    float d2 = csq_half[kk.y] - (p2 + __shfl_xor(p2, 1));
    bool pick1 = (d1 < d2) || (d1 == d2 && kk.x < kk.y);
    int w = pick1 ? kk.x : kk.y;

    const float4* qp = (const float4*)(cb + (size_t)w * DD + h * 32);
    float4* op = (float4*)(quant + (size_t)grow * DD + h * 32);
    float err = 0.f;
#pragma unroll
    for (int j = 0; j < 8; ++j) {
        float4 q = qp[j];
        op[j] = q;
        float ex = q.x - xr4[j].x, ey = q.y - xr4[j].y;
        float ez = q.z - xr4[j].z, ew = q.w - xr4[j].w;
        err += ex * ex + ey * ey + ez * ez + ew * ew;
    }
#pragma unroll
    for (int off = 32; off > 0; off >>= 1) err += __shfl_down(err, off);
    if (lane == 0) atomicAdd(loss_acc, err);
    if (h == 0) {
        idx_int[grow] = w;
        atomicAdd(&counts[w], 1);
    }
}

// --- single block: EMA cluster size, n-reduce, smoothed, scan, loss ---------
__global__ __launch_bounds__(1024) void k_mid(
    const int* __restrict__ counts, const float* __restrict__ ema_cs,
    const float* __restrict__ loss_acc,
    float* __restrict__ new_cs, float* __restrict__ loss_out,
    float* __restrict__ smoothed_inv, int* __restrict__ offsets,
    int* __restrict__ cursor)
{
    int t = threadIdx.x; int lane = t & 63; int w = t >> 6;
    int cnt = counts[t];
    float ncs = DECAY * ema_cs[t] + ONE_MINUS_DECAY * (float)cnt;

    __shared__ float wsumf[16];
    __shared__ int wsumi[16];
    __shared__ float ntot_s;

    float s = ncs;
#pragma unroll
    for (int off = 32; off > 0; off >>= 1) s += __shfl_down(s, off);
    if (lane == 0) wsumf[w] = s;

    int v = cnt;
#pragma unroll
    for (int off = 1; off < 64; off <<= 1) {
        int u = __shfl_up(v, off);
        if (lane >= off) v += u;
    }
    if (lane == 63) wsumi[w] = v;
    __syncthreads();
    if (t == 0) {
        float tt = 0.f;
        for (int i = 0; i < 16; ++i) tt += wsumf[i];
        ntot_s = tt;
    }
    if (w == 0 && lane < 16) {
        int u = wsumi[lane]; int vv = u;
#pragma unroll
        for (int off = 1; off < 16; off <<= 1) {
            int p = __shfl_up(vv, off, 16);
            if ((lane & 15) >= off) vv += p;
        }
        wsumi[lane] = vv - u;
    }
    __syncthreads();
    float n = ntot_s;

    float sm = (ncs + EPSF) / (n + (float)KK * EPSF) * n;
    new_cs[t] = ncs;
    smoothed_inv[t] = 1.0f / sm;

    int excl = wsumi[w] + v - cnt;
    offsets[t] = excl;
    cursor[t] = excl;

    if (t == 0) loss_out[0] = COMMIT * loss_acc[0] / (float)(NN * DD);
}

// --- scatter rows into per-code segments: one int2 {row, code} per position -
__global__ __launch_bounds__(256) void k_scatter(
    int* __restrict__ idx_inout, int* __restrict__ cursor,
    int2* __restrict__ pairs)
{
    int i = blockIdx.x * 256 + threadIdx.x;
    int k = idx_inout[i];
    int pos = atomicAdd(&cursor[k], 1);
    pairs[pos] = make_int2(i, k);
    ((float*)idx_inout)[i] = (float)k;   // own-element read happened above
}

// --- balanced segment sum: each wave 64 sorted rows, shfl-broadcast keys ----
__global__ __launch_bounds__(256) void k_segsum(
    const float* __restrict__ x, const int2* __restrict__ pairs,
    float* __restrict__ dw)
{
    int w = blockIdx.x * 4 + (threadIdx.x >> 6);   // 4096 waves total
    int lane = threadIdx.x & 63;
    int base = w * 64;
    int2 mine = pairs[base + lane];                // coalesced 512B per wave
    float acc = 0.f;
    int cur = __shfl(mine.y, 0);
    for (int r = 0; r < 64; ++r) {
        int code = __shfl(mine.y, r);
        int row  = __shfl(mine.x, r);
        if (code != cur) {                         // wave-uniform
            atomicAdd(&dw[cur * DD + lane], acc);
            acc = 0.f; cur = code;
        }
        acc += x[(size_t)row * DD + lane];         // 256B coalesced gather
    }
    atomicAdd(&dw[cur * DD + lane], acc);
}

// --- EMA weight update + codebook normalize --------------------------------
__global__ __launch_bounds__(256) void k_final(
    const float* __restrict__ dw, const float* __restrict__ ema_w,
    const float* __restrict__ smoothed_inv,
    float* __restrict__ new_ema_w, float* __restrict__ new_cb)
{
    int i = blockIdx.x * 256 + threadIdx.x;
    int k = i >> 6;
    float nw = DECAY * ema_w[i] + ONE_MINUS_DECAY * dw[i];
    new_ema_w[i] = nw;
    new_cb[i] = nw * smoothed_inv[k];
}

extern "C" void kernel_launch(void* const* d_in, const int* in_sizes, int n_in,
                              void* d_out, int out_size, void* d_ws, size_t ws_size,
                              hipStream_t stream)
{
    const float* x      = (const float*)d_in[0];
    const float* cb     = (const float*)d_in[1];
    const float* ema_cs = (const float*)d_in[2];
    const float* ema_w  = (const float*)d_in[3];

    float* out      = (float*)d_out;
    float* quant    = out;                                   // [N*D]
    float* loss_out = out + (size_t)NN * DD;                 // [1]
    int*   idx_reg  = (int*)(out + (size_t)NN * DD + 1);     // [N] (float slot)
    float* new_cb   = out + (size_t)NN * DD + 1 + NN;        // [K*D]
    float* new_cs   = new_cb + (size_t)KK * DD;              // [K]
    float* new_emaw = new_cs + KK;                           // [K*D]

    char* ws = (char*)d_ws;
    float* loss_acc     = (float*)(ws + 0);                  // 256 B
    int*   counts       = (int*)(ws + 256);                  // 4 KB
    float* dw           = (float*)(ws + 4352);               // 256 KB
    int*   offsets      = (int*)(ws + 266496);               // 4 KB
    int*   cursor       = (int*)(ws + 270592);               // 4 KB
    float* csq_half     = (float*)(ws + 274688);             // 4 KB
    float* smoothed_inv = (float*)(ws + 278784);             // 4 KB
    unsigned char* cbhl = (unsigned char*)(ws + 282880);     // 288 KB
    int2*  pairs        = (int2*)(ws + 577792);              // 2 MB

    hipMemsetAsync(d_ws, 0, 266496, stream);   // loss_acc + counts + dw

    k_prep   <<<KK * DD / 256, 256, 0, stream>>>(cb, cbhl, csq_half);
    k_assign <<<NN / 128, 256, 0, stream>>>(x, cb, cbhl, csq_half, quant,
                                            idx_reg, counts, loss_acc);
    k_mid    <<<1, 1024, 0, stream>>>(counts, ema_cs, loss_acc, new_cs,
                                      loss_out, smoothed_inv, offsets, cursor);
    k_scatter<<<NN / 256, 256, 0, stream>>>(idx_reg, cursor, pairs);
    k_segsum <<<NN / 256, 256, 0, stream>>>(x, pairs, dw);
    k_final  <<<KK * DD / 256, 256, 0, stream>>>(dw, ema_w, smoothed_inv,
                                                 new_emaw, new_cb);
}